// Round 13
// baseline (139.888 us; speedup 1.0000x reference)
//
#include <hip/hip_runtime.h>

#define B_ 256
#define K_ 10
#define I_ 1152
#define O_ 16
#define C_ 8
#define BKO (B_*K_*O_)   // 40960
#define NX 72            // i0 blocks (uhat grid.x)
#define LOG2E 1.44269504088896f
// u layout (chunk-major): u[b][ic][k][i127][o], ic in [0,9), i127 in [0,128)
// per-b slice = 368640 B; chunk (b,ic) = 40960 B contiguous.

static __device__ __forceinline__ unsigned short f32_bf16(float f) {
    unsigned int u = __float_as_uint(f);
    u += 0x7FFFu + ((u >> 16) & 1u);           // round-to-nearest-even
    return (unsigned short)(u >> 16);
}

// DPP butterfly add step (full-rate VALU; ctrl is a compile-time const)
template <int CTRL>
static __device__ __forceinline__ float dpp_add(float v) {
    int x = __builtin_amdgcn_update_dpp(0, __float_as_int(v), CTRL, 0xF, 0xF, true);
    return v + __int_as_float(x);
}
// sum over each 16-lane DPP row: xor1, xor2, half-mirror, mirror
static __device__ __forceinline__ float row16_sum(float v) {
    v = dpp_add<0xB1>(v);     // quad_perm(1,0,3,2)  : + lane^1
    v = dpp_add<0x4E>(v);     // quad_perm(2,3,0,1)  : + lane^2
    v = dpp_add<0x141>(v);    // row_half_mirror     : + other quad
    v = dpp_add<0x140>(v);    // row_mirror          : + other half-row
    return v;
}
// sum over 8 consecutive lanes (one i, og=0..7): quad sum + mirrored quad
static __device__ __forceinline__ float quad8_sum(float v) {
    v = dpp_add<0xB1>(v);     // + lane^1
    v = dpp_add<0x4E>(v);     // + lane^2
    v = dpp_add<0x141>(v);    // row_half_mirror: + other quad of the 8
    return v;
}

// ---------------------------------------------------------------------------
// uhat_kernel v9 (unchanged from round 12): chunk-major u store.
// grid (72, 4, 10); 256 thr; 4 b per thread.
// ---------------------------------------------------------------------------
__global__ __launch_bounds__(256) void uhat_kernel(
    const float* __restrict__ x, const float* __restrict__ w,
    unsigned short* __restrict__ u, float* __restrict__ part)
{
    __shared__ float w_lds[16 * 132];   // [ii][o*8+c], stride 132: 2-way max
    __shared__ float p_lds[64 * 17];    // [b_local*17 + o], padded rows
    const int t   = threadIdx.x;
    const int i_l = t & 15, tg = t >> 4;
    const int i0  = blockIdx.x * 16;
    const int b0  = blockIdx.y * 64 + tg * 4;
    const int k   = blockIdx.z;
    const int i   = i0 + i_l;
    const int ic   = blockIdx.x >> 3;              // chunk index
    const int i127 = ((blockIdx.x & 7) << 4) + i_l; // in-chunk i
    const bool row_leader = (i_l == 0);

    float4 xr[4][2];
#pragma unroll
    for (int bb = 0; bb < 4; bb++) {
        const float4* xp = (const float4*)(x + ((size_t)(b0 + bb) * I_ + i) * C_);
        xr[bb][0] = xp[0];
        xr[bb][1] = xp[1];
    }

    {
        const float4* ws = (const float4*)(w + ((size_t)k * I_ + i0) * O_ * C_);
#pragma unroll
        for (int r = 0; r < 2; r++) {
            int idx = r * 256 + t;               // float4 index in 16x128 slab
            int ii = idx >> 5, rem = idx & 31;
            *(float4*)&w_lds[ii * 132 + rem * 4] = ws[idx];
        }
    }
    __syncthreads();

    unsigned int pk[4][8];
#pragma unroll
    for (int oo = 0; oo < 8; oo++) {             // o-pair index
        float d[4][2];
#pragma unroll
        for (int h = 0; h < 2; h++) {
            const int o = oo * 2 + h;
            const float4 w0 = *(const float4*)&w_lds[i_l * 132 + o * 8];
            const float4 w1 = *(const float4*)&w_lds[i_l * 132 + o * 8 + 4];
#pragma unroll
            for (int bb = 0; bb < 4; bb++) {
                d[bb][h] = w0.x*xr[bb][0].x + w0.y*xr[bb][0].y
                         + w0.z*xr[bb][0].z + w0.w*xr[bb][0].w
                         + w1.x*xr[bb][1].x + w1.y*xr[bb][1].y
                         + w1.z*xr[bb][1].z + w1.w*xr[bb][1].w;
            }
        }
        // pass-1 fold: i-sum via DPP rows (16 lanes = the 16 i's)
#pragma unroll
        for (int bb = 0; bb < 4; bb++) {
#pragma unroll
            for (int h = 0; h < 2; h++) {
                const float rs = row16_sum(d[bb][h]);
                if (row_leader)
                    p_lds[(tg * 4 + bb) * 17 + oo * 2 + h] = rs;
            }
        }
#pragma unroll
        for (int bb = 0; bb < 4; bb++)
            pk[bb][oo] = (unsigned int)f32_bf16(d[bb][0]) |
                         ((unsigned int)f32_bf16(d[bb][1]) << 16);
    }
    // fused 32 B u store per (b,k,i): chunk-major layout
#pragma unroll
    for (int bb = 0; bb < 4; bb++) {
        unsigned int* dst = (unsigned int*)
            (u + ((((size_t)(b0 + bb) * 9 + ic) * K_ + k) * 128 + i127) * O_);
        *(uint4*)(dst)     = make_uint4(pk[bb][0], pk[bb][1], pk[bb][2], pk[bb][3]);
        *(uint4*)(dst + 4) = make_uint4(pk[bb][4], pk[bb][5], pk[bb][6], pk[bb][7]);
    }

    // dense partial store: part[x][k][b][o] — wave writes 1024 B contiguous
    __syncthreads();
    {
        const int bl = t >> 2, o4 = (t & 3) * 4;     // b_local, o-quad
        float4 v;
        v.x = p_lds[bl * 17 + o4 + 0];
        v.y = p_lds[bl * 17 + o4 + 1];
        v.z = p_lds[bl * 17 + o4 + 2];
        v.w = p_lds[bl * 17 + o4 + 3];
        *(float4*)&part[(((size_t)blockIdx.x * K_ + k) * 256
                         + blockIdx.y * 64 + bl) * O_ + o4] = v;
    }
}

// ---------------------------------------------------------------------------
// route_all v17 = v16 + (a) ping-pong A/B chunk buffers: zero P=Q copies
// (was 10 v_mov x 18 chunks/thread), same 20-dword liveness; (b) exp2
// pre-scale: v_lds holds v*log2e, CHUNK uses exp2f -> saves the per-exp
// mul (180/thread); (c) vmcnt-FIFO ordering: chunk-0 loads issue BEFORE
// the pass-3 staging burst; pass-3's first HBM prefetch issues before the
// LDS-chunk compute.  Chunk processing order 0..8 unchanged.
// ---------------------------------------------------------------------------

// stage one contiguous 40 KB chunk with 1024 threads: 2560 x 16 B units.
static __device__ __forceinline__ void stage_chunk_1024(
    const char* __restrict__ chunk_base, int t, char* lds_buf)
{
#pragma unroll
    for (int r = 0; r < 3; r++) {
        if (r < 2 || t < 512) {
            const int L = r * 1024 + t;       // 16B-unit index in [0,2560)
            const char* src = chunk_base + (size_t)L * 16;
            char* dst = lds_buf + ((size_t)(r * 1024 + (t & ~63)) * 16);
            __builtin_amdgcn_global_load_lds(
                (const __attribute__((address_space(1))) unsigned int*)src,
                (__attribute__((address_space(3))) unsigned int*)dst,
                16, 0, 0);
        }
    }
}

#define LOAD_CHUNK(BUF, SRC) do {                                             \
    _Pragma("unroll")                                                         \
    for (int k = 0; k < K_; k++)                                              \
        BUF[k] = *(const unsigned int*)((SRC) + k * 4096 + base);             \
} while (0)

// one chunk's softmax+accumulate given the 10 per-k dwords in PP[].
// v_lds is pre-scaled by log2e; exp2f = e^logit.
#define CHUNK_OG8(PP) do {                                                    \
    float c_[K_]; float Z = 0.f;                                              \
    _Pragma("unroll")                                                         \
    for (int k = 0; k < K_; k++) {                                            \
        const float f0 = __uint_as_float(PP[k] << 16);                        \
        const float f1 = __uint_as_float(PP[k] & 0xffff0000u);                \
        const float2 vk = *(const float2*)&v_lds[k * 16 + og * 2];            \
        float lk = f0 * vk.x + f1 * vk.y;                                     \
        lk = quad8_sum(lk);                                                   \
        c_[k] = __builtin_exp2f(lk); Z += c_[k];                              \
    }                                                                         \
    const float inv = 1.0f / Z;                                               \
    _Pragma("unroll")                                                         \
    for (int k = 0; k < K_; k++) {                                            \
        const float ck = c_[k] * inv;                                         \
        acc[k][0] = fmaf(ck, __uint_as_float(PP[k] << 16),         acc[k][0]);\
        acc[k][1] = fmaf(ck, __uint_as_float(PP[k] & 0xffff0000u), acc[k][1]);\
    }                                                                         \
} while (0)

// pass-2 sweep: ping-pong register path over chunks 0..8; also issues the
// LDS stages for chunks 0-2 (retired by the next __syncthreads).
static __device__ __forceinline__ void sweep_pass2(
    const char* __restrict__ ubb, int t, int i_l, int og,
    const float* __restrict__ v_lds, float acc[K_][2], char* __restrict__ ubuf)
{
#pragma unroll
    for (int k = 0; k < K_; k++) { acc[k][0] = 0.f; acc[k][1] = 0.f; }

    const int base = i_l * 32 + og * 4;       // bytes within a (chunk,k) slab

    unsigned int A[K_], B[K_];
    LOAD_CHUNK(A, ubb);                       // chunk 0 first in the FIFO

    stage_chunk_1024(ubb,          t, ubuf);              // pass-3 chunks
    stage_chunk_1024(ubb + 40960,  t, ubuf + 40960);
    stage_chunk_1024(ubb + 81920,  t, ubuf + 81920);

    LOAD_CHUNK(B, ubb + 40960);               // chunk 1

    // pairs (0,1),(2,3),(4,5),(6,7) then tail chunk 8; zero copies.
#pragma unroll 1
    for (int g = 0; g < 4; g++) {
        CHUNK_OG8(A);
        LOAD_CHUNK(A, ubb + (size_t)(2 * g + 2) * 40960);   // 2g+2 <= 8
        CHUNK_OG8(B);
        if (g < 3) LOAD_CHUNK(B, ubb + (size_t)(2 * g + 3) * 40960);
    }
    CHUNK_OG8(A);                             // chunk 8
}

// pass-3 sweep: chunks 0-2 from LDS, 3-8 ping-pong from global.
static __device__ __forceinline__ void sweep_pass3(
    const char* __restrict__ ubb, int i_l, int og,
    const float* __restrict__ v_lds, float acc[K_][2],
    const char* __restrict__ ubuf)
{
#pragma unroll
    for (int k = 0; k < K_; k++) { acc[k][0] = 0.f; acc[k][1] = 0.f; }

    const int base = i_l * 32 + og * 4;

    unsigned int A[K_], B[K_];
    LOAD_CHUNK(A, ubb + 3 * 40960);           // HBM prefetch under LDS compute

    // chunks 0-2: LDS-resident (bit-identical bytes, same order)
#pragma unroll 1
    for (int ic = 0; ic < 3; ic++) {
        const char* cb = ubuf + (size_t)ic * 40960;
        unsigned int P[K_];
#pragma unroll
        for (int k = 0; k < K_; k++)
            P[k] = *(const unsigned int*)(cb + k * 4096 + base);
        CHUNK_OG8(P);
    }

    LOAD_CHUNK(B, ubb + 4 * 40960);
    // pairs (3,4),(5,6) then tail (7,8)
#pragma unroll 1
    for (int g = 0; g < 2; g++) {
        CHUNK_OG8(A);
        LOAD_CHUNK(A, ubb + (size_t)(2 * g + 5) * 40960);   // 5,7
        CHUNK_OG8(B);
        LOAD_CHUNK(B, ubb + (size_t)(2 * g + 6) * 40960);   // 6,8
    }
    CHUNK_OG8(A);                             // chunk 7
    CHUNK_OG8(B);                             // chunk 8
}

// reduce acc over the 8 i-positions of each wave; deposit per-wave sums.
// red: [16 waves][160]
static __device__ __forceinline__ void block_reduce(
    float acc[K_][2], float* __restrict__ red, int lane, int wv)
{
#pragma unroll
    for (int k = 0; k < K_; k++)
#pragma unroll
        for (int j = 0; j < 2; j++) {
            float a = acc[k][j];
            a += __shfl_xor(a, 8); a += __shfl_xor(a, 16); a += __shfl_xor(a, 32);
            acc[k][j] = a;
        }
    if (lane < 8) {
#pragma unroll
        for (int k = 0; k < K_; k++)
            *(float2*)&red[wv * 160 + k * 16 + lane * 2] =
                make_float2(acc[k][0], acc[k][1]);
    }
    __syncthreads();
}

// sum the 16 per-wave partials for element t (t < 160)
static __device__ __forceinline__ float sum16(const float* __restrict__ red, int t)
{
    float s = 0.f;
#pragma unroll
    for (int wgi = 0; wgi < 16; wgi++) s += red[wgi * 160 + t];
    return s;
}

// squash for element t<160: 16-lane o-group norm reduce
static __device__ __forceinline__ float squash_v(float s) {
    float n2 = s * s;
    n2 += __shfl_xor(n2, 1); n2 += __shfl_xor(n2, 2);
    n2 += __shfl_xor(n2, 4); n2 += __shfl_xor(n2, 8);
    const float norm = sqrtf(n2);
    return s * (n2 / (1.0f + n2) / (norm + 1e-9f));
}

// ---------------------------------------------------------------------------
// route_all v17: passes 2+3; pass 1 from part[x][k][b][o].
// grid (256), 1024 thr (16 waves, 4/SIMD).  LDS 131.6 KB (3 chunks + red).
// ---------------------------------------------------------------------------
__global__ __launch_bounds__(1024) void route_all(
    const unsigned short* __restrict__ u, const float* __restrict__ part,
    float* __restrict__ out)
{
    __shared__ __align__(16) char ubuf[3 * 40960];
    __shared__ float red[16 * 160];
    __shared__ float v_lds[160];
    __shared__ float v1_lds[160];

    const int t    = threadIdx.x;
    const int og   = t & 7, i_l = t >> 3;   // og: o-pair idx, i_l in 0..127
    const int b    = blockIdx.x;
    const int lane = t & 63, wv = t >> 6;   // wv in 0..15

    const char* ubb = (const char*)u + (size_t)b * 368640;
    float acc[K_][2];

    // ---- prologue: s1 = sum over the 72 i-blocks; v1 = squash(s1/K) ----
    if (t < 160) {
        const int k = t >> 4, o = t & 15;
        const float* pb = part + ((size_t)k * 256 + b) * O_ + o;
        float s = 0.f;
#pragma unroll
        for (int xb = 0; xb < NX; xb++)
            s += pb[(size_t)xb * BKO];
        float v = squash_v(s * (1.0f / K_));
        v1_lds[t] = v;                        // unscaled, for telescoped update
        v_lds[t]  = v * LOG2E;                // pre-scaled for exp2 logits
    }
    __syncthreads();

    // ---- pass 2: logits from v1 (also stages chunks 0-2 into LDS) ----
    sweep_pass2(ubb, t, i_l, og, v_lds, acc, ubuf);
    block_reduce(acc, red, lane, wv);   // __syncthreads drains the stages
    float v12 = 0.f;
    if (t < 160) v12 = v1_lds[t] + squash_v(sum16(red, t));
    __syncthreads();          // all sum16 reads done before v_lds overwrite
    if (t < 160) v_lds[t] = v12 * LOG2E;
    __syncthreads();

    // ---- pass 3: logits from v1+v2 (telescoped); chunks 0-2 from LDS ----
    sweep_pass3(ubb, i_l, og, v_lds, acc, ubuf);
    block_reduce(acc, red, lane, wv);
    if (t < 160)
        out[(size_t)b * 160 + t] = squash_v(sum16(red, t));
}

// ---------------------------------------------------------------------------
extern "C" void kernel_launch(void* const* d_in, const int* in_sizes, int n_in,
                              void* d_out, int out_size, void* d_ws, size_t ws_size,
                              hipStream_t stream)
{
    const float* x = (const float*)d_in[0];
    const float* w = (const float*)d_in[1];
    float* outp = (float*)d_out;

    float* part = (float*)d_ws;                          // NX*BKO f32 = 11.8 MB
    unsigned short* u = (unsigned short*)(part + (size_t)NX * BKO);  // 94.4 MB

    uhat_kernel<<<dim3(72, 4, 10), 256, 0, stream>>>(x, w, u, part);
    route_all<<<B_, 1024, 0, stream>>>(u, part, outp);
}

// Round 14
// 121.106 us; speedup vs baseline: 1.1551x; 1.1551x over previous
//
#include <hip/hip_runtime.h>

#define B_ 256
#define K_ 10
#define I_ 1152
#define O_ 16
#define C_ 8
#define BKO (B_*K_*O_)   // 40960
#define NX 72            // i0 blocks (uhat grid.x)
// u layout (chunk-major): u[b][ic][k][i127][o], ic in [0,9), i127 in [0,128)
// per-b slice = 9*10*128*16 shorts = 368640 B; chunk (b,ic) = 40960 B contiguous.

static __device__ __forceinline__ unsigned short f32_bf16(float f) {
    unsigned int u = __float_as_uint(f);
    u += 0x7FFFu + ((u >> 16) & 1u);           // round-to-nearest-even
    return (unsigned short)(u >> 16);
}

// DPP butterfly add step (full-rate VALU; ctrl is a compile-time const)
template <int CTRL>
static __device__ __forceinline__ float dpp_add(float v) {
    int x = __builtin_amdgcn_update_dpp(0, __float_as_int(v), CTRL, 0xF, 0xF, true);
    return v + __int_as_float(x);
}
// sum over each 16-lane DPP row: xor1, xor2, half-mirror, mirror
static __device__ __forceinline__ float row16_sum(float v) {
    v = dpp_add<0xB1>(v);     // quad_perm(1,0,3,2)  : + lane^1
    v = dpp_add<0x4E>(v);     // quad_perm(2,3,0,1)  : + lane^2
    v = dpp_add<0x141>(v);    // row_half_mirror     : + other quad
    v = dpp_add<0x140>(v);    // row_mirror          : + other half-row
    return v;
}
// sum over 8 consecutive lanes (one i, og=0..7): quad sum + mirrored quad
static __device__ __forceinline__ float quad8_sum(float v) {
    v = dpp_add<0xB1>(v);     // + lane^1
    v = dpp_add<0x4E>(v);     // + lane^2
    v = dpp_add<0x141>(v);    // row_half_mirror: + other quad of the 8
    return v;
}

// ---------------------------------------------------------------------------
// uhat_kernel v9: chunk-major u store.  grid (72, 4, 10); 256 thr; 4 b/thread.
// ---------------------------------------------------------------------------
__global__ __launch_bounds__(256) void uhat_kernel(
    const float* __restrict__ x, const float* __restrict__ w,
    unsigned short* __restrict__ u, float* __restrict__ part)
{
    __shared__ float w_lds[16 * 132];   // [ii][o*8+c], stride 132: 2-way max
    __shared__ float p_lds[64 * 17];    // [b_local*17 + o], padded rows
    const int t   = threadIdx.x;
    const int i_l = t & 15, tg = t >> 4;
    const int i0  = blockIdx.x * 16;
    const int b0  = blockIdx.y * 64 + tg * 4;
    const int k   = blockIdx.z;
    const int i   = i0 + i_l;
    const int ic   = blockIdx.x >> 3;              // chunk index
    const int i127 = ((blockIdx.x & 7) << 4) + i_l; // in-chunk i
    const bool row_leader = (i_l == 0);

    float4 xr[4][2];
#pragma unroll
    for (int bb = 0; bb < 4; bb++) {
        const float4* xp = (const float4*)(x + ((size_t)(b0 + bb) * I_ + i) * C_);
        xr[bb][0] = xp[0];
        xr[bb][1] = xp[1];
    }

    {
        const float4* ws = (const float4*)(w + ((size_t)k * I_ + i0) * O_ * C_);
#pragma unroll
        for (int r = 0; r < 2; r++) {
            int idx = r * 256 + t;               // float4 index in 16x128 slab
            int ii = idx >> 5, rem = idx & 31;
            *(float4*)&w_lds[ii * 132 + rem * 4] = ws[idx];
        }
    }
    __syncthreads();

    unsigned int pk[4][8];
#pragma unroll
    for (int oo = 0; oo < 8; oo++) {             // o-pair index
        float d[4][2];
#pragma unroll
        for (int h = 0; h < 2; h++) {
            const int o = oo * 2 + h;
            const float4 w0 = *(const float4*)&w_lds[i_l * 132 + o * 8];
            const float4 w1 = *(const float4*)&w_lds[i_l * 132 + o * 8 + 4];
#pragma unroll
            for (int bb = 0; bb < 4; bb++) {
                d[bb][h] = w0.x*xr[bb][0].x + w0.y*xr[bb][0].y
                         + w0.z*xr[bb][0].z + w0.w*xr[bb][0].w
                         + w1.x*xr[bb][1].x + w1.y*xr[bb][1].y
                         + w1.z*xr[bb][1].z + w1.w*xr[bb][1].w;
            }
        }
        // pass-1 fold: i-sum via DPP rows (16 lanes = the 16 i's)
#pragma unroll
        for (int bb = 0; bb < 4; bb++) {
#pragma unroll
            for (int h = 0; h < 2; h++) {
                const float rs = row16_sum(d[bb][h]);
                if (row_leader)
                    p_lds[(tg * 4 + bb) * 17 + oo * 2 + h] = rs;
            }
        }
#pragma unroll
        for (int bb = 0; bb < 4; bb++)
            pk[bb][oo] = (unsigned int)f32_bf16(d[bb][0]) |
                         ((unsigned int)f32_bf16(d[bb][1]) << 16);
    }
    // fused 32 B u store per (b,k,i): chunk-major layout
#pragma unroll
    for (int bb = 0; bb < 4; bb++) {
        unsigned int* dst = (unsigned int*)
            (u + ((((size_t)(b0 + bb) * 9 + ic) * K_ + k) * 128 + i127) * O_);
        *(uint4*)(dst)     = make_uint4(pk[bb][0], pk[bb][1], pk[bb][2], pk[bb][3]);
        *(uint4*)(dst + 4) = make_uint4(pk[bb][4], pk[bb][5], pk[bb][6], pk[bb][7]);
    }

    // dense partial store: part[x][k][b][o] — wave writes 1024 B contiguous
    __syncthreads();
    {
        const int bl = t >> 2, o4 = (t & 3) * 4;     // b_local, o-quad
        float4 v;
        v.x = p_lds[bl * 17 + o4 + 0];
        v.y = p_lds[bl * 17 + o4 + 1];
        v.z = p_lds[bl * 17 + o4 + 2];
        v.w = p_lds[bl * 17 + o4 + 3];
        *(float4*)&part[(((size_t)blockIdx.x * K_ + k) * 256
                         + blockIdx.y * 64 + bl) * O_ + o4] = v;
    }
}

// ---------------------------------------------------------------------------
// route_all v16 (REVERTED from v17: the ping-pong 2x CHUNK expansion pushed
// liveness past the 64-VGPR/1024-thr cap -> 24.7 MB spill writes, 57 us.
// v16 measured: VGPR 52, WRITE 160 B, FETCH 91.5 MB, total 120.49 us.)
// Pass-2: rolled P/Q register path, contiguous 40 KB chunk windows; also
// stages chunks 0-2 into LDS for pass-3.  Pass-3: chunks 0-2 from LDS.
// ---------------------------------------------------------------------------

// stage one contiguous 40 KB chunk with 1024 threads: 2560 x 16 B units.
static __device__ __forceinline__ void stage_chunk_1024(
    const char* __restrict__ chunk_base, int t, char* lds_buf)
{
#pragma unroll
    for (int r = 0; r < 3; r++) {
        if (r < 2 || t < 512) {
            const int L = r * 1024 + t;       // 16B-unit index in [0,2560)
            const char* src = chunk_base + (size_t)L * 16;
            char* dst = lds_buf + ((size_t)(r * 1024 + (t & ~63)) * 16);
            __builtin_amdgcn_global_load_lds(
                (const __attribute__((address_space(1))) unsigned int*)src,
                (__attribute__((address_space(3))) unsigned int*)dst,
                16, 0, 0);
        }
    }
}

// one chunk's softmax+accumulate given the 10 per-k dwords in PP[]
#define CHUNK_OG8(PP) do {                                                    \
    float c_[K_]; float Z = 0.f;                                              \
    _Pragma("unroll")                                                         \
    for (int k = 0; k < K_; k++) {                                            \
        const float f0 = __uint_as_float(PP[k] << 16);                        \
        const float f1 = __uint_as_float(PP[k] & 0xffff0000u);                \
        const float2 vk = *(const float2*)&v_lds[k * 16 + og * 2];            \
        float lk = f0 * vk.x + f1 * vk.y;                                     \
        lk = quad8_sum(lk);                                                   \
        c_[k] = __expf(lk); Z += c_[k];                                       \
    }                                                                         \
    const float inv = 1.0f / Z;                                               \
    _Pragma("unroll")                                                         \
    for (int k = 0; k < K_; k++) {                                            \
        const float ck = c_[k] * inv;                                         \
        acc[k][0] = fmaf(ck, __uint_as_float(PP[k] << 16),         acc[k][0]);\
        acc[k][1] = fmaf(ck, __uint_as_float(PP[k] & 0xffff0000u), acc[k][1]);\
    }                                                                         \
} while (0)

// pass-2 sweep: register path over all 9 chunks (contiguous windows);
// also issues the LDS stages for chunks 0-2 (retired by next __syncthreads).
static __device__ __forceinline__ void sweep_pass2(
    const char* __restrict__ ubb, int t, int i_l, int og,
    const float* __restrict__ v_lds, float acc[K_][2], char* __restrict__ ubuf)
{
#pragma unroll
    for (int k = 0; k < K_; k++) { acc[k][0] = 0.f; acc[k][1] = 0.f; }

    stage_chunk_1024(ubb,          t, ubuf);
    stage_chunk_1024(ubb + 40960,  t, ubuf + 40960);
    stage_chunk_1024(ubb + 81920,  t, ubuf + 81920);

    const int base = i_l * 32 + og * 4;       // bytes within a (chunk,k) slab

    unsigned int P[K_], Q[K_];
#pragma unroll
    for (int k = 0; k < K_; k++)
        P[k] = *(const unsigned int*)(ubb + k * 4096 + base);

#pragma unroll 1
    for (int ic = 0; ic < 9; ic++) {
        if (ic + 1 < 9) {
            const char* nb = ubb + (size_t)(ic + 1) * 40960;
#pragma unroll
            for (int k = 0; k < K_; k++)
                Q[k] = *(const unsigned int*)(nb + k * 4096 + base);
        }
        CHUNK_OG8(P);
#pragma unroll
        for (int k = 0; k < K_; k++) P[k] = Q[k];
    }
}

// pass-3 sweep: chunks 0-2 from LDS, 3-8 via register prefetch.
static __device__ __forceinline__ void sweep_pass3(
    const char* __restrict__ ubb, int i_l, int og,
    const float* __restrict__ v_lds, float acc[K_][2],
    const char* __restrict__ ubuf)
{
#pragma unroll
    for (int k = 0; k < K_; k++) { acc[k][0] = 0.f; acc[k][1] = 0.f; }

    const int base = i_l * 32 + og * 4;

    // chunks 0-2: LDS-resident (bit-identical bytes, same order)
#pragma unroll 1
    for (int ic = 0; ic < 3; ic++) {
        const char* cb = ubuf + (size_t)ic * 40960;
        unsigned int P[K_];
#pragma unroll
        for (int k = 0; k < K_; k++)
            P[k] = *(const unsigned int*)(cb + k * 4096 + base);
        CHUNK_OG8(P);
    }
    // chunks 3-8: register path
    unsigned int P[K_], Q[K_];
#pragma unroll
    for (int k = 0; k < K_; k++)
        P[k] = *(const unsigned int*)(ubb + 3 * 40960 + k * 4096 + base);
#pragma unroll 1
    for (int ic = 3; ic < 9; ic++) {
        if (ic + 1 < 9) {
            const char* nb = ubb + (size_t)(ic + 1) * 40960;
#pragma unroll
            for (int k = 0; k < K_; k++)
                Q[k] = *(const unsigned int*)(nb + k * 4096 + base);
        }
        CHUNK_OG8(P);
#pragma unroll
        for (int k = 0; k < K_; k++) P[k] = Q[k];
    }
}

// reduce acc over the 8 i-positions of each wave; deposit per-wave sums.
// red: [16 waves][160]
static __device__ __forceinline__ void block_reduce(
    float acc[K_][2], float* __restrict__ red, int lane, int wv)
{
#pragma unroll
    for (int k = 0; k < K_; k++)
#pragma unroll
        for (int j = 0; j < 2; j++) {
            float a = acc[k][j];
            a += __shfl_xor(a, 8); a += __shfl_xor(a, 16); a += __shfl_xor(a, 32);
            acc[k][j] = a;
        }
    if (lane < 8) {
#pragma unroll
        for (int k = 0; k < K_; k++)
            *(float2*)&red[wv * 160 + k * 16 + lane * 2] =
                make_float2(acc[k][0], acc[k][1]);
    }
    __syncthreads();
}

// sum the 16 per-wave partials for element t (t < 160)
static __device__ __forceinline__ float sum16(const float* __restrict__ red, int t)
{
    float s = 0.f;
#pragma unroll
    for (int wgi = 0; wgi < 16; wgi++) s += red[wgi * 160 + t];
    return s;
}

// squash for element t<160: 16-lane o-group norm reduce
static __device__ __forceinline__ float squash_v(float s) {
    float n2 = s * s;
    n2 += __shfl_xor(n2, 1); n2 += __shfl_xor(n2, 2);
    n2 += __shfl_xor(n2, 4); n2 += __shfl_xor(n2, 8);
    const float norm = sqrtf(n2);
    return s * (n2 / (1.0f + n2) / (norm + 1e-9f));
}

// ---------------------------------------------------------------------------
// route_all v16: passes 2+3; pass 1 from part[x][k][b][o].
// grid (256), 1024 thr (16 waves, 4/SIMD).  LDS 131.6 KB (3 chunks + red).
// ---------------------------------------------------------------------------
__global__ __launch_bounds__(1024) void route_all(
    const unsigned short* __restrict__ u, const float* __restrict__ part,
    float* __restrict__ out)
{
    __shared__ __align__(16) char ubuf[3 * 40960];
    __shared__ float red[16 * 160];
    __shared__ float v_lds[160];
    __shared__ float v1_lds[160];

    const int t    = threadIdx.x;
    const int og   = t & 7, i_l = t >> 3;   // og: o-pair idx, i_l in 0..127
    const int b    = blockIdx.x;
    const int lane = t & 63, wv = t >> 6;   // wv in 0..15

    const char* ubb = (const char*)u + (size_t)b * 368640;
    float acc[K_][2];

    // ---- prologue: s1 = sum over the 72 i-blocks; v1 = squash(s1/K) ----
    if (t < 160) {
        const int k = t >> 4, o = t & 15;
        const float* pb = part + ((size_t)k * 256 + b) * O_ + o;
        float s = 0.f;
#pragma unroll
        for (int xb = 0; xb < NX; xb++)
            s += pb[(size_t)xb * BKO];
        float v = squash_v(s * (1.0f / K_));
        v1_lds[t] = v;
        v_lds[t]  = v;
    }
    __syncthreads();

    // ---- pass 2: logits from v1 (also stages chunks 0-2 into LDS) ----
    sweep_pass2(ubb, t, i_l, og, v_lds, acc, ubuf);
    block_reduce(acc, red, lane, wv);   // __syncthreads drains the stages
    float v12 = 0.f;
    if (t < 160) v12 = v1_lds[t] + squash_v(sum16(red, t));
    __syncthreads();          // all sum16 reads done before v_lds overwrite
    if (t < 160) v_lds[t] = v12;
    __syncthreads();

    // ---- pass 3: logits from v1+v2 (telescoped); chunks 0-2 from LDS ----
    sweep_pass3(ubb, i_l, og, v_lds, acc, ubuf);
    block_reduce(acc, red, lane, wv);
    if (t < 160)
        out[(size_t)b * 160 + t] = squash_v(sum16(red, t));
}

// ---------------------------------------------------------------------------
extern "C" void kernel_launch(void* const* d_in, const int* in_sizes, int n_in,
                              void* d_out, int out_size, void* d_ws, size_t ws_size,
                              hipStream_t stream)
{
    const float* x = (const float*)d_in[0];
    const float* w = (const float*)d_in[1];
    float* outp = (float*)d_out;

    float* part = (float*)d_ws;                          // NX*BKO f32 = 11.8 MB
    unsigned short* u = (unsigned short*)(part + (size_t)NX * BKO);  // 94.4 MB

    uhat_kernel<<<dim3(72, 4, 10), 256, 0, stream>>>(x, w, u, part);
    route_all<<<B_, 1024, 0, stream>>>(u, part, outp);
}